// Round 3
// baseline (289.324 us; speedup 1.0000x reference)
//
#include <hip/hip_runtime.h>
#include <hip/hip_bf16.h>

// B=2, S=2048, D=1024, H=16, KVH=4, DK=64, R=16, groups=4, SCALING=1.0
// out (f32): (B,S,1024)

typedef __attribute__((ext_vector_type(8))) short short8;
typedef __attribute__((ext_vector_type(4))) float f32x4;
typedef __attribute__((ext_vector_type(16))) float f32x16;
typedef __attribute__((ext_vector_type(2))) unsigned int uint2v;

#define DEV static __device__ __forceinline__

DEV unsigned short f32_to_bf16(float f) {
  unsigned int u = __float_as_uint(f);
  u += 0x7FFFu + ((u >> 16) & 1u);   // RNE
  return (unsigned short)(u >> 16);
}

DEV unsigned int cvt_pk_bf16(float lo, float hi) {
  unsigned int r;
  asm("v_cvt_pk_bf16_f32 %0, %1, %2" : "=v"(r) : "v"(lo), "v"(hi));
  return r;
}

DEV short8 cvt8(f32x4 a, f32x4 b) {
  short8 r;
  r[0] = (short)f32_to_bf16(a[0]); r[1] = (short)f32_to_bf16(a[1]);
  r[2] = (short)f32_to_bf16(a[2]); r[3] = (short)f32_to_bf16(a[3]);
  r[4] = (short)f32_to_bf16(b[0]); r[5] = (short)f32_to_bf16(b[1]);
  r[6] = (short)f32_to_bf16(b[2]); r[7] = (short)f32_to_bf16(b[3]);
  return r;
}

DEV short8 ld_cvt8(const float* p) {
  f32x4 a = *(const f32x4*)p;
  f32x4 b = *(const f32x4*)(p + 4);
  return cvt8(a, b);
}

// ---------- all four W_eff^T in one launch ----------
// WT[n][k] = W[k][n] + sum_r A[k][r]*B[r][n], bf16.  grid(160,64) block(16,16)
__global__ __launch_bounds__(256) void weff_all_kernel(
    const float* __restrict__ Wq, const float* __restrict__ Aq, const float* __restrict__ Bq, unsigned short* __restrict__ WqT,
    const float* __restrict__ Wk, const float* __restrict__ Ak, const float* __restrict__ Bk, unsigned short* __restrict__ WkT,
    const float* __restrict__ Wv, const float* __restrict__ Av, const float* __restrict__ Bv, unsigned short* __restrict__ WvT,
    const float* __restrict__ Wo, const float* __restrict__ Ao, const float* __restrict__ Bo, unsigned short* __restrict__ WoT) {
  __shared__ float tile[16][17];
  const int bx = blockIdx.x;
  const float *W, *A, *Bm; unsigned short* WT; int N, nb;
  if (bx < 64)       { W = Wq; A = Aq; Bm = Bq; WT = WqT; N = 1024; nb = bx; }
  else if (bx < 80)  { W = Wk; A = Ak; Bm = Bk; WT = WkT; N = 256;  nb = bx - 64; }
  else if (bx < 96)  { W = Wv; A = Av; Bm = Bv; WT = WvT; N = 256;  nb = bx - 80; }
  else               { W = Wo; A = Ao; Bm = Bo; WT = WoT; N = 1024; nb = bx - 96; }
  const int tx = threadIdx.x, ty = threadIdx.y;
  const int n0 = nb * 16, k0 = blockIdx.y * 16;
  const int n = n0 + tx, k = k0 + ty;
  float acc = W[(size_t)k * N + n];
#pragma unroll
  for (int r = 0; r < 16; ++r) acc += A[k * 16 + r] * Bm[(size_t)r * N + n];
  tile[ty][tx] = acc;
  __syncthreads();
  WT[(size_t)(n0 + ty) * 1024 + (k0 + tx)] = f32_to_bf16(tile[tx][ty]);
}

// ---------- GEMM core: C(tile 128M x 64N) = X(Mx1024) * WT^T ----------
// 4 waves 2(m)x2(n); wave computes 64x32 (4x2 frags of 16x16x32).
// F32IN: A operand loaded as f32 and converted (fuses the cast).
// OUTMODE: 0 bf16 row-major; 1 f32 row-major; 2 Vt [(b*4+kv)*64+d][2048];
//          3 K head-major [(b*4+kv)*2048+s][64]
template <int OUTMODE, bool F32IN>
DEV void gemm_core(const void* __restrict__ Xv, const unsigned short* __restrict__ WT,
                   void* __restrict__ Cv, int N, int m0b, int n0b) {
  constexpr int K = 1024;
  const int w = threadIdx.x >> 6, l = threadIdx.x & 63;
  const int lr = l & 15, lg = l >> 4;
  const int m0 = m0b + (w >> 1) * 64;
  const int n0 = n0b + (w & 1) * 32;
  const float* xf = (const float*)Xv + (size_t)(m0 + lr) * K + lg * 8;
  const unsigned short* xh = (const unsigned short*)Xv + (size_t)(m0 + lr) * K + lg * 8;
  const unsigned short* wrow = WT + (size_t)(n0 + lr) * K + lg * 8;

  f32x4 acc[4][2];
#pragma unroll
  for (int mm = 0; mm < 4; ++mm)
#pragma unroll
    for (int nn = 0; nn < 2; ++nn) acc[mm][nn] = f32x4{0.f, 0.f, 0.f, 0.f};

  short8 a[4], bfr[2];
#pragma unroll
  for (int mm = 0; mm < 4; ++mm)
    a[mm] = F32IN ? ld_cvt8(xf + (size_t)mm * 16 * K)
                  : *(const short8*)(xh + (size_t)mm * 16 * K);
#pragma unroll
  for (int nn = 0; nn < 2; ++nn) bfr[nn] = *(const short8*)(wrow + (size_t)nn * 16 * K);

  for (int k0 = 0; k0 < K; k0 += 32) {
    short8 an[4], bn[2];
    const bool more = (k0 + 32 < K);
    if (more) {
#pragma unroll
      for (int mm = 0; mm < 4; ++mm)
        an[mm] = F32IN ? ld_cvt8(xf + (size_t)mm * 16 * K + k0 + 32)
                       : *(const short8*)(xh + (size_t)mm * 16 * K + k0 + 32);
#pragma unroll
      for (int nn = 0; nn < 2; ++nn) bn[nn] = *(const short8*)(wrow + (size_t)nn * 16 * K + k0 + 32);
    }
#pragma unroll
    for (int mm = 0; mm < 4; ++mm)
#pragma unroll
      for (int nn = 0; nn < 2; ++nn)
        acc[mm][nn] = __builtin_amdgcn_mfma_f32_16x16x32_bf16(a[mm], bfr[nn], acc[mm][nn], 0, 0, 0);
    if (more) {
#pragma unroll
      for (int mm = 0; mm < 4; ++mm) a[mm] = an[mm];
#pragma unroll
      for (int nn = 0; nn < 2; ++nn) bfr[nn] = bn[nn];
    }
  }

#pragma unroll
  for (int mm = 0; mm < 4; ++mm)
#pragma unroll
    for (int nn = 0; nn < 2; ++nn)
#pragma unroll
      for (int i = 0; i < 4; ++i) {
        const int row = m0 + mm * 16 + lg * 4 + i;
        const int col = n0 + nn * 16 + lr;
        const float v = acc[mm][nn][i];
        if (OUTMODE == 0) {
          ((unsigned short*)Cv)[(size_t)row * N + col] = f32_to_bf16(v);
        } else if (OUTMODE == 1) {
          ((float*)Cv)[(size_t)row * N + col] = v;
        } else if (OUTMODE == 2) {
          ((unsigned short*)Cv)[((size_t)((row >> 11) * 4 + (col >> 6)) * 64 + (col & 63)) * 2048 + (row & 2047)] = f32_to_bf16(v);
        } else {
          ((unsigned short*)Cv)[((size_t)((row >> 11) * 4 + (col >> 6)) * 2048 + (row & 2047)) * 64 + (col & 63)] = f32_to_bf16(v);
        }
      }
}

// fused Q/K/V projections (+cast). Q: 512 blocks, K: 128, V: 128.
__global__ __launch_bounds__(256) void qkv_kernel(
    const float* __restrict__ query, const float* __restrict__ key, const float* __restrict__ value,
    const unsigned short* __restrict__ WqT, const unsigned short* __restrict__ WkT, const unsigned short* __restrict__ WvT,
    unsigned short* __restrict__ Qw, unsigned short* __restrict__ Khm, unsigned short* __restrict__ Vtw) {
  const int bx = blockIdx.x;
  if (bx < 512) {
    gemm_core<0, true>(query, WqT, Qw, 1024, (bx >> 4) * 128, (bx & 15) * 64);
  } else if (bx < 640) {
    const int t = bx - 512;
    gemm_core<3, true>(key, WkT, Khm, 256, (t >> 2) * 128, (t & 3) * 64);
  } else {
    const int t = bx - 640;
    gemm_core<2, true>(value, WvT, Vtw, 256, (t >> 2) * 128, (t & 3) * 64);
  }
}

// O projection: bf16 in, f32 out. 512 blocks.
__global__ __launch_bounds__(256) void ogemm_kernel(const unsigned short* __restrict__ Xw,
                                                    const unsigned short* __restrict__ WoT,
                                                    float* __restrict__ out) {
  const int bx = blockIdx.x;
  gemm_core<1, false>(Xw, WoT, out, 1024, (bx >> 4) * 128, (bx & 15) * 64);
}

// ---------- flash attention, swapped-QK 32x32, intra-block k-split ----------
// Q [B][S][1024] bf16; Kh [(b*4+kv)*2048+s][64] bf16; Vt [(b*4+kv)*64+d][2048] bf16
// grid (64, 16, 2) block 256. Block owns q rows [qt*32, qt*32+32); wave w takes
// k-tiles kt = w, w+4, ... (64 k each), partial (m,l,O); LDS combine at end.
__global__ __launch_bounds__(256) void attn3_kernel(const unsigned short* __restrict__ Q,
                                                    const unsigned short* __restrict__ Kh,
                                                    const unsigned short* __restrict__ Vt,
                                                    unsigned short* __restrict__ Xo) {
  const int l = threadIdx.x & 63, w = threadIdx.x >> 6;
  const int cq = l & 31, hi = l >> 5;
  const int qt = (int)(gridDim.x - 1 - blockIdx.x);   // longest-first
  const int h = blockIdx.y, b = blockIdx.z;
  const int kv = h >> 2;
  const int q0 = qt * 32;
  const int q = q0 + cq;
  const float LOG2E = 1.44269504f;
  const float slope2 = exp2f(-(float)(h + 1)) * LOG2E;
  const float qscale = 0.125f * LOG2E;

  const unsigned short* qp = Q + ((size_t)(b * 2048 + q)) * 1024 + h * 64 + hi * 8;
  short8 qf[4];
#pragma unroll
  for (int c = 0; c < 4; ++c) qf[c] = *(const short8*)(qp + c * 16);

  const unsigned short* Kb = Kh + ((size_t)(b * 4 + kv) * 2048) * 64 + hi * 8;
  const unsigned short* Vb = Vt + ((size_t)(b * 4 + kv) * 64 + cq) * 2048 + hi * 8;

  f32x16 oA, oB;
#pragma unroll
  for (int r = 0; r < 16; ++r) { oA[r] = 0.f; oB[r] = 0.f; }
  float mrun = -3e38f, lrun = 0.f;

  const float fhi = 4.0f * (float)hi;
  const int nkt = (q0 + 31) / 64 + 1;

  for (int kt = w; kt < nkt; kt += 4) {
    const int k0 = kt * 64;
    const unsigned short* kp = Kb + (size_t)(k0 + cq) * 64;

    f32x16 sA, sB;
#pragma unroll
    for (int r = 0; r < 16; ++r) { sA[r] = 0.f; sB[r] = 0.f; }
#pragma unroll
    for (int c = 0; c < 4; ++c) {
      short8 kfa = *(const short8*)(kp + c * 16);
      short8 kfb = *(const short8*)(kp + 32 * 64 + c * 16);
      sA = __builtin_amdgcn_mfma_f32_32x32x16_bf16(kfa, qf[c], sA, 0, 0, 0);
      sB = __builtin_amdgcn_mfma_f32_32x32x16_bf16(kfb, qf[c], sB, 0, 0, 0);
    }

    const float fhb   = fmaf(slope2, fhi, slope2 * (float)(k0 - q));
    const float fhb32 = fmaf(slope2, fhi, slope2 * (float)(k0 + 32 - q));
    const bool masked = (kt == nkt - 1);
    const int ikq4 = k0 - q + 4 * hi;
    float svA[16], svB[16];
#pragma unroll
    for (int r = 0; r < 16; ++r) {
      const int koffc = (r & 3) + 8 * (r >> 2);
      const float kf = (float)koffc;
      float va = fmaf(sA[r], qscale, fmaf(slope2, kf, fhb));
      float vb = fmaf(sB[r], qscale, fmaf(slope2, kf, fhb32));
      if (masked) {
        if (ikq4 + koffc > 0) va = -3e38f;
        if (ikq4 + koffc + 32 > 0) vb = -3e38f;
      }
      svA[r] = va; svB[r] = vb;
    }

    // max: 4 partial accumulators (shorter dep chain), one cross-half shuffle
    float m0_ = fmaxf(svA[0], svB[0]), m1_ = fmaxf(svA[1], svB[1]);
    float m2_ = fmaxf(svA[2], svB[2]), m3_ = fmaxf(svA[3], svB[3]);
#pragma unroll
    for (int r = 4; r < 16; r += 4) {
      m0_ = fmaxf(m0_, fmaxf(svA[r], svB[r]));
      m1_ = fmaxf(m1_, fmaxf(svA[r + 1], svB[r + 1]));
      m2_ = fmaxf(m2_, fmaxf(svA[r + 2], svB[r + 2]));
      m3_ = fmaxf(m3_, fmaxf(svA[r + 3], svB[r + 3]));
    }
    float mx = fmaxf(fmaxf(m0_, m1_), fmaxf(m2_, m3_));
    mx = fmaxf(mx, __shfl_xor(mx, 32));
    const float mnew = fmaxf(mrun, mx);
    const float fsc = exp2f(mrun - mnew);
    mrun = mnew;

    float pA[16], pB[16];
    float l0_ = 0.f, l1_ = 0.f, l2_ = 0.f, l3_ = 0.f;
#pragma unroll
    for (int r = 0; r < 16; r += 4) {
      pA[r] = exp2f(svA[r] - mnew);     pB[r] = exp2f(svB[r] - mnew);
      pA[r + 1] = exp2f(svA[r + 1] - mnew); pB[r + 1] = exp2f(svB[r + 1] - mnew);
      pA[r + 2] = exp2f(svA[r + 2] - mnew); pB[r + 2] = exp2f(svB[r + 2] - mnew);
      pA[r + 3] = exp2f(svA[r + 3] - mnew); pB[r + 3] = exp2f(svB[r + 3] - mnew);
      l0_ += pA[r] + pB[r];
      l1_ += pA[r + 1] + pB[r + 1];
      l2_ += pA[r + 2] + pB[r + 2];
      l3_ += pA[r + 3] + pB[r + 3];
    }
    float ls = (l0_ + l1_) + (l2_ + l3_);
    ls += __shfl_xor(ls, 32);
    lrun = fmaf(lrun, fsc, ls);
#pragma unroll
    for (int r = 0; r < 16; ++r) { oA[r] *= fsc; oB[r] *= fsc; }

#define PV_HALF(PARR, KBASE)                                                          \
    {                                                                                 \
      _Pragma("unroll")                                                               \
      for (int g = 0; g < 2; ++g) {                                                   \
        unsigned int a0 = cvt_pk_bf16(PARR[g * 8 + 0], PARR[g * 8 + 1]);              \
        unsigned int b0 = cvt_pk_bf16(PARR[g * 8 + 4], PARR[g * 8 + 5]);              \
        unsigned int a1 = cvt_pk_bf16(PARR[g * 8 + 2], PARR[g * 8 + 3]);              \
        unsigned int b1 = cvt_pk_bf16(PARR[g * 8 + 6], PARR[g * 8 + 7]);              \
        uint2v r0 = __builtin_amdgcn_permlane32_swap(a0, b0, false, false);           \
        uint2v r1 = __builtin_amdgcn_permlane32_swap(a1, b1, false, false);           \
        union { unsigned int u[4]; short8 s; } pb_;                                   \
        pb_.u[0] = r0[0]; pb_.u[1] = r1[0]; pb_.u[2] = r0[1]; pb_.u[3] = r1[1];       \
        const unsigned short* vp = Vb + (KBASE) + g * 16;                             \
        short8 v0 = *(const short8*)(vp);                                             \
        short8 v1 = *(const short8*)(vp + (size_t)32 * 2048);                         \
        oA = __builtin_amdgcn_mfma_f32_32x32x16_bf16(v0, pb_.s, oA, 0, 0, 0);         \
        oB = __builtin_amdgcn_mfma_f32_32x32x16_bf16(v1, pb_.s, oB, 0, 0, 0);         \
      }                                                                               \
    }
    PV_HALF(pA, k0)
    PV_HALF(pB, k0 + 32)
#undef PV_HALF
  }

  // ---- cross-wave combine ----
  __shared__ float mbuf[4][32];
  __shared__ float lbuf[4][32];
  __shared__ float obuf[4][32][68];   // stride 68: 16B-aligned rows, 4-bank spread

  if (hi == 0) { mbuf[w][cq] = mrun; lbuf[w][cq] = lrun; }
#pragma unroll
  for (int g = 0; g < 4; ++g) {
    f32x4 t0 = {oA[g * 4 + 0], oA[g * 4 + 1], oA[g * 4 + 2], oA[g * 4 + 3]};
    f32x4 t1 = {oB[g * 4 + 0], oB[g * 4 + 1], oB[g * 4 + 2], oB[g * 4 + 3]};
    *(f32x4*)&obuf[w][cq][8 * g + 4 * hi] = t0;
    *(f32x4*)&obuf[w][cq][8 * g + 4 * hi + 32] = t1;
  }
  __syncthreads();

  const int tq = threadIdx.x >> 3;
  const int d0 = (threadIdx.x & 7) * 8;
  float mw[4], mstar;
#pragma unroll
  for (int w4 = 0; w4 < 4; ++w4) mw[w4] = mbuf[w4][tq];
  mstar = fmaxf(fmaxf(mw[0], mw[1]), fmaxf(mw[2], mw[3]));
  float sc[4], lstar = 0.f;
#pragma unroll
  for (int w4 = 0; w4 < 4; ++w4) {
    sc[w4] = exp2f(mw[w4] - mstar);
    lstar = fmaf(sc[w4], lbuf[w4][tq], lstar);
  }
  float av[8];
#pragma unroll
  for (int j = 0; j < 8; ++j) av[j] = 0.f;
#pragma unroll
  for (int w4 = 0; w4 < 4; ++w4) {
    f32x4 u0 = *(const f32x4*)&obuf[w4][tq][d0];
    f32x4 u1 = *(const f32x4*)&obuf[w4][tq][d0 + 4];
#pragma unroll
    for (int j = 0; j < 4; ++j) {
      av[j] = fmaf(sc[w4], u0[j], av[j]);
      av[j + 4] = fmaf(sc[w4], u1[j], av[j + 4]);
    }
  }
  const float rinv = __builtin_amdgcn_rcpf(lstar);
  short8 ov;
#pragma unroll
  for (int j = 0; j < 8; ++j) ov[j] = (short)f32_to_bf16(av[j] * rinv);
  *(short8*)(Xo + ((size_t)(b * 2048 + q0 + tq)) * 1024 + h * 64 + d0) = ov;
}

extern "C" void kernel_launch(void* const* d_in, const int* in_sizes, int n_in,
                              void* d_out, int out_size, void* d_ws, size_t ws_size,
                              hipStream_t stream) {
  const float* query = (const float*)d_in[0];
  const float* key   = (const float*)d_in[1];
  const float* value = (const float*)d_in[2];
  const float* Wq = (const float*)d_in[3];
  const float* Wk = (const float*)d_in[4];
  const float* Wv = (const float*)d_in[5];
  const float* Wo = (const float*)d_in[6];
  const float* Aq = (const float*)d_in[7];
  const float* Bq = (const float*)d_in[8];
  const float* Ak = (const float*)d_in[9];
  const float* Bk = (const float*)d_in[10];
  const float* Av = (const float*)d_in[11];
  const float* Bv = (const float*)d_in[12];
  const float* Ao = (const float*)d_in[13];
  const float* Bo = (const float*)d_in[14];

  unsigned short* ws  = (unsigned short*)d_ws;
  unsigned short* WqT = ws;                       // 1M elems
  unsigned short* WkT = WqT + 1024 * 1024;        // 256K
  unsigned short* WvT = WkT + 256 * 1024;         // 256K
  unsigned short* WoT = WvT + 256 * 1024;         // 1M
  unsigned short* Qw  = WoT + 1024 * 1024;        // 4M   [B][S][1024]
  unsigned short* Khm = Qw + 4096 * 1024;         // 1M   [(b*4+kv)*2048+s][64]
  unsigned short* Vtw = Khm + 4096 * 256;         // 1M   [(b*4+kv)*64+d][2048]
  unsigned short* Xw  = Vtw + 4096 * 256;         // 4M   attn out [B][S][1024]

  weff_all_kernel<<<dim3(160, 64), dim3(16, 16), 0, stream>>>(
      Wq, Aq, Bq, WqT, Wk, Ak, Bk, WkT, Wv, Av, Bv, WvT, Wo, Ao, Bo, WoT);

  qkv_kernel<<<768, 256, 0, stream>>>(query, key, value, WqT, WkT, WvT, Qw, Khm, Vtw);

  attn3_kernel<<<dim3(64, 16, 2), 256, 0, stream>>>(Qw, Khm, Vtw, Xw);

  ogemm_kernel<<<512, 256, 0, stream>>>(Xw, WoT, (float*)d_out);
}

// Round 4
// 178.554 us; speedup vs baseline: 1.6204x; 1.6204x over previous
//
#include <hip/hip_runtime.h>
#include <hip/hip_bf16.h>

// B=2, S=2048, D=1024, H=16, KVH=4, DK=64, R=16, groups=4, SCALING=1.0
// out (f32): (B,S,1024)

typedef __attribute__((ext_vector_type(8))) short short8;
typedef __attribute__((ext_vector_type(4))) float f32x4;
typedef __attribute__((ext_vector_type(16))) float f32x16;
typedef __attribute__((ext_vector_type(2))) unsigned int uint2v;

#define DEV static __device__ __forceinline__

DEV unsigned short f32_to_bf16(float f) {
  unsigned int u = __float_as_uint(f);
  u += 0x7FFFu + ((u >> 16) & 1u);   // RNE
  return (unsigned short)(u >> 16);
}

DEV unsigned int cvt_pk_bf16(float lo, float hi) {
  unsigned int r;
  asm("v_cvt_pk_bf16_f32 %0, %1, %2" : "=v"(r) : "v"(lo), "v"(hi));
  return r;
}

DEV short8 cvt8(f32x4 a, f32x4 b) {
  short8 r;
  r[0] = (short)f32_to_bf16(a[0]); r[1] = (short)f32_to_bf16(a[1]);
  r[2] = (short)f32_to_bf16(a[2]); r[3] = (short)f32_to_bf16(a[3]);
  r[4] = (short)f32_to_bf16(b[0]); r[5] = (short)f32_to_bf16(b[1]);
  r[6] = (short)f32_to_bf16(b[2]); r[7] = (short)f32_to_bf16(b[3]);
  return r;
}

// bijective XCD-chunk swizzle (nblk % 8 == 0): consecutive virtual ids share an XCD
DEV int xcd_chunk(int bid, int nblk) {
  const int chunk = nblk >> 3;
  return (bid & 7) * chunk + (bid >> 3);
}

// ---------- all four W_eff^T in one launch ----------
__global__ __launch_bounds__(256) void weff_all_kernel(
    const float* __restrict__ Wq, const float* __restrict__ Aq, const float* __restrict__ Bq, unsigned short* __restrict__ WqT,
    const float* __restrict__ Wk, const float* __restrict__ Ak, const float* __restrict__ Bk, unsigned short* __restrict__ WkT,
    const float* __restrict__ Wv, const float* __restrict__ Av, const float* __restrict__ Bv, unsigned short* __restrict__ WvT,
    const float* __restrict__ Wo, const float* __restrict__ Ao, const float* __restrict__ Bo, unsigned short* __restrict__ WoT) {
  __shared__ float tile[16][17];
  const int bx = blockIdx.x;
  const float *W, *A, *Bm; unsigned short* WT; int N, nb;
  if (bx < 64)       { W = Wq; A = Aq; Bm = Bq; WT = WqT; N = 1024; nb = bx; }
  else if (bx < 80)  { W = Wk; A = Ak; Bm = Bk; WT = WkT; N = 256;  nb = bx - 64; }
  else if (bx < 96)  { W = Wv; A = Av; Bm = Bv; WT = WvT; N = 256;  nb = bx - 80; }
  else               { W = Wo; A = Ao; Bm = Bo; WT = WoT; N = 1024; nb = bx - 96; }
  const int tx = threadIdx.x, ty = threadIdx.y;
  const int n0 = nb * 16, k0 = blockIdx.y * 16;
  const int n = n0 + tx, k = k0 + ty;
  float acc = W[(size_t)k * N + n];
#pragma unroll
  for (int r = 0; r < 16; ++r) acc += A[k * 16 + r] * Bm[(size_t)r * N + n];
  tile[ty][tx] = acc;
  __syncthreads();
  WT[(size_t)(n0 + ty) * 1024 + (k0 + tx)] = f32_to_bf16(tile[tx][ty]);
}

// ---------- LDS-staged GEMM core: C(tile 128x128) = X(Mx1024) * WT^T ----------
// 4 waves (2m x 2n); wave computes 64x64 (4x4 frags of 16x16x32 bf16 MFMA).
// A staged via regs with fused f32->bf16 cast (F32IN) into padded LDS (RS=40),
// B (bf16 WT rows) likewise. Double-buffered, 1 barrier per K-step (BK=32).
// OUTMODE: 0 bf16 row-major; 1 f32 row-major; 2 Vt [(b*4+kv)*64+d][2048];
//          3 K head-major [(b*4+kv)*2048+s][64]
template <int OUTMODE, bool F32IN>
DEV void gemm_lds_core(const void* __restrict__ Xv, const unsigned short* __restrict__ WT,
                       void* __restrict__ Cv, int N, int m0b, int n0b,
                       unsigned short* lds) {
  constexpr int K = 1024, BK = 32, NT = K / BK;   // 32 K-steps
  constexpr int RS = 40;                          // padded row stride (bf16 elems)
  constexpr int MATS = 128 * RS;                  // elems per matrix per buffer
  const int tid = threadIdx.x;
  const int w = tid >> 6, l = tid & 63;
  const int lr = l & 15, lg = l >> 4;
  const int m0 = m0b + (w >> 1) * 64;
  const int n0 = n0b + (w & 1) * 64;
  const int wabase = (w >> 1) * 64;   // A row base in LDS for this wave
  const int wbbase = (w & 1) * 64;    // B row base in LDS for this wave

  // staging: thread covers (row = tid>>1, half = tid&1): 16 k-elems
  const int srow = tid >> 1, shalf = tid & 1;
  const float* xf = (const float*)Xv + (size_t)(m0b + srow) * K + shalf * 16;
  const unsigned short* xh = (const unsigned short*)Xv + (size_t)(m0b + srow) * K + shalf * 16;
  const unsigned short* wsrc = WT + (size_t)(n0b + srow) * K + shalf * 16;

  f32x4 acc[4][4];
#pragma unroll
  for (int mm = 0; mm < 4; ++mm)
#pragma unroll
    for (int nn = 0; nn < 4; ++nn) acc[mm][nn] = f32x4{0.f, 0.f, 0.f, 0.f};

  f32x4 ar[4];      // F32IN staging regs
  short8 arh[2];    // bf16 staging regs
  short8 brh[2];

#define G_LOAD(T)                                                     \
  {                                                                   \
    const int off_ = (T) * BK;                                        \
    if (F32IN) {                                                      \
      ar[0] = *(const f32x4*)(xf + off_);                             \
      ar[1] = *(const f32x4*)(xf + off_ + 4);                         \
      ar[2] = *(const f32x4*)(xf + off_ + 8);                         \
      ar[3] = *(const f32x4*)(xf + off_ + 12);                        \
    } else {                                                          \
      arh[0] = *(const short8*)(xh + off_);                           \
      arh[1] = *(const short8*)(xh + off_ + 8);                       \
    }                                                                 \
    brh[0] = *(const short8*)(wsrc + off_);                           \
    brh[1] = *(const short8*)(wsrc + off_ + 8);                       \
  }

#define S_WRITE(BUF)                                                  \
  {                                                                   \
    unsigned short* Ab_ = lds + (BUF) * 2 * MATS;                     \
    unsigned short* Bb_ = Ab_ + MATS;                                 \
    unsigned short* ap_ = Ab_ + srow * RS + shalf * 16;               \
    if (F32IN) {                                                      \
      *(short8*)(ap_) = cvt8(ar[0], ar[1]);                           \
      *(short8*)(ap_ + 8) = cvt8(ar[2], ar[3]);                       \
    } else {                                                          \
      *(short8*)(ap_) = arh[0];                                       \
      *(short8*)(ap_ + 8) = arh[1];                                   \
    }                                                                 \
    unsigned short* bp_ = Bb_ + srow * RS + shalf * 16;               \
    *(short8*)(bp_) = brh[0];                                         \
    *(short8*)(bp_ + 8) = brh[1];                                     \
  }

  G_LOAD(0)
  S_WRITE(0)
  __syncthreads();
  int cur = 0;

  for (int t = 0; t < NT; ++t) {
    if (t + 1 < NT) G_LOAD(t + 1)

    const unsigned short* Ab = lds + cur * 2 * MATS;
    const unsigned short* Bb = Ab + MATS;
    short8 af[4], bfg[4];
#pragma unroll
    for (int mm = 0; mm < 4; ++mm)
      af[mm] = *(const short8*)(Ab + (wabase + mm * 16 + lr) * RS + lg * 8);
#pragma unroll
    for (int nn = 0; nn < 4; ++nn)
      bfg[nn] = *(const short8*)(Bb + (wbbase + nn * 16 + lr) * RS + lg * 8);

#pragma unroll
    for (int mm = 0; mm < 4; ++mm)
#pragma unroll
      for (int nn = 0; nn < 4; ++nn)
        acc[mm][nn] = __builtin_amdgcn_mfma_f32_16x16x32_bf16(af[mm], bfg[nn], acc[mm][nn], 0, 0, 0);

    if (t + 1 < NT) {
      S_WRITE(cur ^ 1)
      __syncthreads();
      cur ^= 1;
    }
  }
#undef G_LOAD
#undef S_WRITE

#pragma unroll
  for (int mm = 0; mm < 4; ++mm)
#pragma unroll
    for (int nn = 0; nn < 4; ++nn)
#pragma unroll
      for (int i = 0; i < 4; ++i) {
        const int row = m0 + mm * 16 + lg * 4 + i;
        const int col = n0 + nn * 16 + lr;
        const float v = acc[mm][nn][i];
        if (OUTMODE == 0) {
          ((unsigned short*)Cv)[(size_t)row * N + col] = f32_to_bf16(v);
        } else if (OUTMODE == 1) {
          ((float*)Cv)[(size_t)row * N + col] = v;
        } else if (OUTMODE == 2) {
          ((unsigned short*)Cv)[((size_t)((row >> 11) * 4 + (col >> 6)) * 64 + (col & 63)) * 2048 + (row & 2047)] = f32_to_bf16(v);
        } else {
          ((unsigned short*)Cv)[((size_t)((row >> 11) * 4 + (col >> 6)) * 2048 + (row & 2047)) * 64 + (col & 63)] = f32_to_bf16(v);
        }
      }
}

// fused Q/K/V projections (+cast). Q: 256 blocks (32m x 8n), K: 64 (32m x 2n), V: 64.
__global__ __launch_bounds__(256, 3) void qkv_kernel(
    const float* __restrict__ query, const float* __restrict__ key, const float* __restrict__ value,
    const unsigned short* __restrict__ WqT, const unsigned short* __restrict__ WkT, const unsigned short* __restrict__ WvT,
    unsigned short* __restrict__ Qw, unsigned short* __restrict__ Khm, unsigned short* __restrict__ Vtw) {
  __shared__ unsigned short lds[2 * 2 * 128 * 40];   // 40 KB
  const int bx = blockIdx.x;
  if (bx < 256) {
    const int v = xcd_chunk(bx, 256);
    gemm_lds_core<0, true>(query, WqT, Qw, 1024, (v >> 3) * 128, (v & 7) * 128, lds);
  } else if (bx < 320) {
    const int v = xcd_chunk(bx - 256, 64);
    gemm_lds_core<3, true>(key, WkT, Khm, 256, (v >> 1) * 128, (v & 1) * 128, lds);
  } else {
    const int v = xcd_chunk(bx - 320, 64);
    gemm_lds_core<2, true>(value, WvT, Vtw, 256, (v >> 1) * 128, (v & 1) * 128, lds);
  }
}

// O projection: bf16 in, f32 out. 256 blocks (32m x 8n).
__global__ __launch_bounds__(256, 3) void ogemm_kernel(const unsigned short* __restrict__ Xw,
                                                       const unsigned short* __restrict__ WoT,
                                                       float* __restrict__ out) {
  __shared__ unsigned short lds[2 * 2 * 128 * 40];
  const int v = xcd_chunk(blockIdx.x, 256);
  gemm_lds_core<1, false>(Xw, WoT, out, 1024, (v >> 3) * 128, (v & 7) * 128, lds);
}

// ---------- flash attention, swapped-QK 32x32, intra-block k-split ----------
__global__ __launch_bounds__(256) void attn3_kernel(const unsigned short* __restrict__ Q,
                                                    const unsigned short* __restrict__ Kh,
                                                    const unsigned short* __restrict__ Vt,
                                                    unsigned short* __restrict__ Xo) {
  const int l = threadIdx.x & 63, w = threadIdx.x >> 6;
  const int cq = l & 31, hi = l >> 5;
  const int qt = (int)(gridDim.x - 1 - blockIdx.x);   // longest-first
  const int h = blockIdx.y, b = blockIdx.z;
  const int kv = h >> 2;
  const int q0 = qt * 32;
  const int q = q0 + cq;
  const float LOG2E = 1.44269504f;
  const float slope2 = exp2f(-(float)(h + 1)) * LOG2E;
  const float qscale = 0.125f * LOG2E;

  const unsigned short* qp = Q + ((size_t)(b * 2048 + q)) * 1024 + h * 64 + hi * 8;
  short8 qf[4];
#pragma unroll
  for (int c = 0; c < 4; ++c) qf[c] = *(const short8*)(qp + c * 16);

  const unsigned short* Kb = Kh + ((size_t)(b * 4 + kv) * 2048) * 64 + hi * 8;
  const unsigned short* Vb = Vt + ((size_t)(b * 4 + kv) * 64 + cq) * 2048 + hi * 8;

  f32x16 oA, oB;
#pragma unroll
  for (int r = 0; r < 16; ++r) { oA[r] = 0.f; oB[r] = 0.f; }
  float mrun = -3e38f, lrun = 0.f;

  const float fhi = 4.0f * (float)hi;
  const int nkt = (q0 + 31) / 64 + 1;

  for (int kt = w; kt < nkt; kt += 4) {
    const int k0 = kt * 64;
    const unsigned short* kp = Kb + (size_t)(k0 + cq) * 64;

    f32x16 sA, sB;
#pragma unroll
    for (int r = 0; r < 16; ++r) { sA[r] = 0.f; sB[r] = 0.f; }
#pragma unroll
    for (int c = 0; c < 4; ++c) {
      short8 kfa = *(const short8*)(kp + c * 16);
      short8 kfb = *(const short8*)(kp + 32 * 64 + c * 16);
      sA = __builtin_amdgcn_mfma_f32_32x32x16_bf16(kfa, qf[c], sA, 0, 0, 0);
      sB = __builtin_amdgcn_mfma_f32_32x32x16_bf16(kfb, qf[c], sB, 0, 0, 0);
    }

    const float fhb   = fmaf(slope2, fhi, slope2 * (float)(k0 - q));
    const float fhb32 = fmaf(slope2, fhi, slope2 * (float)(k0 + 32 - q));
    const bool masked = (kt == nkt - 1);
    const int ikq4 = k0 - q + 4 * hi;
    float svA[16], svB[16];
#pragma unroll
    for (int r = 0; r < 16; ++r) {
      const int koffc = (r & 3) + 8 * (r >> 2);
      const float kf = (float)koffc;
      float va = fmaf(sA[r], qscale, fmaf(slope2, kf, fhb));
      float vb = fmaf(sB[r], qscale, fmaf(slope2, kf, fhb32));
      if (masked) {
        if (ikq4 + koffc > 0) va = -3e38f;
        if (ikq4 + koffc + 32 > 0) vb = -3e38f;
      }
      svA[r] = va; svB[r] = vb;
    }

    float m0_ = fmaxf(svA[0], svB[0]), m1_ = fmaxf(svA[1], svB[1]);
    float m2_ = fmaxf(svA[2], svB[2]), m3_ = fmaxf(svA[3], svB[3]);
#pragma unroll
    for (int r = 4; r < 16; r += 4) {
      m0_ = fmaxf(m0_, fmaxf(svA[r], svB[r]));
      m1_ = fmaxf(m1_, fmaxf(svA[r + 1], svB[r + 1]));
      m2_ = fmaxf(m2_, fmaxf(svA[r + 2], svB[r + 2]));
      m3_ = fmaxf(m3_, fmaxf(svA[r + 3], svB[r + 3]));
    }
    float mx = fmaxf(fmaxf(m0_, m1_), fmaxf(m2_, m3_));
    mx = fmaxf(mx, __shfl_xor(mx, 32));
    const float mnew = fmaxf(mrun, mx);
    const float fsc = exp2f(mrun - mnew);
    mrun = mnew;

    float pA[16], pB[16];
    float l0_ = 0.f, l1_ = 0.f, l2_ = 0.f, l3_ = 0.f;
#pragma unroll
    for (int r = 0; r < 16; r += 4) {
      pA[r] = exp2f(svA[r] - mnew);     pB[r] = exp2f(svB[r] - mnew);
      pA[r + 1] = exp2f(svA[r + 1] - mnew); pB[r + 1] = exp2f(svB[r + 1] - mnew);
      pA[r + 2] = exp2f(svA[r + 2] - mnew); pB[r + 2] = exp2f(svB[r + 2] - mnew);
      pA[r + 3] = exp2f(svA[r + 3] - mnew); pB[r + 3] = exp2f(svB[r + 3] - mnew);
      l0_ += pA[r] + pB[r];
      l1_ += pA[r + 1] + pB[r + 1];
      l2_ += pA[r + 2] + pB[r + 2];
      l3_ += pA[r + 3] + pB[r + 3];
    }
    float ls = (l0_ + l1_) + (l2_ + l3_);
    ls += __shfl_xor(ls, 32);
    lrun = fmaf(lrun, fsc, ls);
#pragma unroll
    for (int r = 0; r < 16; ++r) { oA[r] *= fsc; oB[r] *= fsc; }

#define PV_HALF(PARR, KBASE)                                                          \
    {                                                                                 \
      _Pragma("unroll")                                                               \
      for (int g = 0; g < 2; ++g) {                                                   \
        unsigned int a0 = cvt_pk_bf16(PARR[g * 8 + 0], PARR[g * 8 + 1]);              \
        unsigned int b0 = cvt_pk_bf16(PARR[g * 8 + 4], PARR[g * 8 + 5]);              \
        unsigned int a1 = cvt_pk_bf16(PARR[g * 8 + 2], PARR[g * 8 + 3]);              \
        unsigned int b1 = cvt_pk_bf16(PARR[g * 8 + 6], PARR[g * 8 + 7]);              \
        uint2v r0 = __builtin_amdgcn_permlane32_swap(a0, b0, false, false);           \
        uint2v r1 = __builtin_amdgcn_permlane32_swap(a1, b1, false, false);           \
        union { unsigned int u[4]; short8 s; } pb_;                                   \
        pb_.u[0] = r0[0]; pb_.u[1] = r1[0]; pb_.u[2] = r0[1]; pb_.u[3] = r1[1];       \
        const unsigned short* vp = Vb + (KBASE) + g * 16;                             \
        short8 v0 = *(const short8*)(vp);                                             \
        short8 v1 = *(const short8*)(vp + (size_t)32 * 2048);                         \
        oA = __builtin_amdgcn_mfma_f32_32x32x16_bf16(v0, pb_.s, oA, 0, 0, 0);         \
        oB = __builtin_amdgcn_mfma_f32_32x32x16_bf16(v1, pb_.s, oB, 0, 0, 0);         \
      }                                                                               \
    }
    PV_HALF(pA, k0)
    PV_HALF(pB, k0 + 32)
#undef PV_HALF
  }

  // ---- cross-wave combine ----
  __shared__ float mbuf[4][32];
  __shared__ float lbuf[4][32];
  __shared__ float obuf[4][32][68];

  if (hi == 0) { mbuf[w][cq] = mrun; lbuf[w][cq] = lrun; }
#pragma unroll
  for (int g = 0; g < 4; ++g) {
    f32x4 t0 = {oA[g * 4 + 0], oA[g * 4 + 1], oA[g * 4 + 2], oA[g * 4 + 3]};
    f32x4 t1 = {oB[g * 4 + 0], oB[g * 4 + 1], oB[g * 4 + 2], oB[g * 4 + 3]};
    *(f32x4*)&obuf[w][cq][8 * g + 4 * hi] = t0;
    *(f32x4*)&obuf[w][cq][8 * g + 4 * hi + 32] = t1;
  }
  __syncthreads();

  const int tq = threadIdx.x >> 3;
  const int d0 = (threadIdx.x & 7) * 8;
  float mw[4], mstar;
#pragma unroll
  for (int w4 = 0; w4 < 4; ++w4) mw[w4] = mbuf[w4][tq];
  mstar = fmaxf(fmaxf(mw[0], mw[1]), fmaxf(mw[2], mw[3]));
  float sc[4], lstar = 0.f;
#pragma unroll
  for (int w4 = 0; w4 < 4; ++w4) {
    sc[w4] = exp2f(mw[w4] - mstar);
    lstar = fmaf(sc[w4], lbuf[w4][tq], lstar);
  }
  float av[8];
#pragma unroll
  for (int j = 0; j < 8; ++j) av[j] = 0.f;
#pragma unroll
  for (int w4 = 0; w4 < 4; ++w4) {
    f32x4 u0 = *(const f32x4*)&obuf[w4][tq][d0];
    f32x4 u1 = *(const f32x4*)&obuf[w4][tq][d0 + 4];
#pragma unroll
    for (int j = 0; j < 4; ++j) {
      av[j] = fmaf(sc[w4], u0[j], av[j]);
      av[j + 4] = fmaf(sc[w4], u1[j], av[j + 4]);
    }
  }
  const float rinv = __builtin_amdgcn_rcpf(lstar);
  short8 ov;
#pragma unroll
  for (int j = 0; j < 8; ++j) ov[j] = (short)f32_to_bf16(av[j] * rinv);
  *(short8*)(Xo + ((size_t)(b * 2048 + q0 + tq)) * 1024 + h * 64 + d0) = ov;
}

extern "C" void kernel_launch(void* const* d_in, const int* in_sizes, int n_in,
                              void* d_out, int out_size, void* d_ws, size_t ws_size,
                              hipStream_t stream) {
  const float* query = (const float*)d_in[0];
  const float* key   = (const float*)d_in[1];
  const float* value = (const float*)d_in[2];
  const float* Wq = (const float*)d_in[3];
  const float* Wk = (const float*)d_in[4];
  const float* Wv = (const float*)d_in[5];
  const float* Wo = (const float*)d_in[6];
  const float* Aq = (const float*)d_in[7];
  const float* Bq = (const float*)d_in[8];
  const float* Ak = (const float*)d_in[9];
  const float* Bk = (const float*)d_in[10];
  const float* Av = (const float*)d_in[11];
  const float* Bv = (const float*)d_in[12];
  const float* Ao = (const float*)d_in[13];
  const float* Bo = (const float*)d_in[14];

  unsigned short* ws  = (unsigned short*)d_ws;
  unsigned short* WqT = ws;                       // 1M elems
  unsigned short* WkT = WqT + 1024 * 1024;        // 256K
  unsigned short* WvT = WkT + 256 * 1024;         // 256K
  unsigned short* WoT = WvT + 256 * 1024;         // 1M
  unsigned short* Qw  = WoT + 1024 * 1024;        // 4M   [B][S][1024]
  unsigned short* Khm = Qw + 4096 * 1024;         // 1M   [(b*4+kv)*2048+s][64]
  unsigned short* Vtw = Khm + 4096 * 256;         // 1M   [(b*4+kv)*64+d][2048]
  unsigned short* Xw  = Vtw + 4096 * 256;         // 4M   attn out [B][S][1024]

  weff_all_kernel<<<dim3(160, 64), dim3(16, 16), 0, stream>>>(
      Wq, Aq, Bq, WqT, Wk, Ak, Bk, WkT, Wv, Av, Bv, WvT, Wo, Ao, Bo, WoT);

  qkv_kernel<<<384, 256, 0, stream>>>(query, key, value, WqT, WkT, WvT, Qw, Khm, Vtw);

  attn3_kernel<<<dim3(64, 16, 2), 256, 0, stream>>>(Qw, Khm, Vtw, Xw);

  ogemm_kernel<<<256, 256, 0, stream>>>(Xw, WoT, (float*)d_out);
}